// Round 5
// baseline (185.331 us; speedup 1.0000x reference)
//
#include <hip/hip_runtime.h>
#include <math.h>

#define BATCH 2
#define SEQ   2048
#define DIM   1024
#define NH    16
#define HD    64
#define MTOT  4096

typedef __attribute__((ext_vector_type(8)))  short bf16x8;
typedef __attribute__((ext_vector_type(4)))  float f32x4;
typedef __attribute__((ext_vector_type(16))) float f32x16;

__device__ __forceinline__ ushort f2bf(float f) {
    union { float f; unsigned u; } v; v.f = f;
    unsigned r = v.u + 0x7fffu + ((v.u >> 16) & 1u);
    return (ushort)(r >> 16);
}

__device__ __forceinline__ unsigned cvtpk_bf16(float lo, float hi) {
    unsigned r;
    asm("v_cvt_pk_bf16_f32 %0, %1, %2" : "=v"(r) : "v"(lo), "v"(hi));
    return r;
}

// ---------------------------------------------------------------------------
// casts
// ---------------------------------------------------------------------------
__global__ __launch_bounds__(256)
void cast_x_k(const float* __restrict__ s, ushort* __restrict__ d, int n4)
{
    for (int i = blockIdx.x * blockDim.x + threadIdx.x; i < n4;
         i += gridDim.x * blockDim.x) {
        float4 v = ((const float4*)s)[i];
        ushort4 o;
        o.x = f2bf(v.x); o.y = f2bf(v.y); o.z = f2bf(v.z); o.w = f2bf(v.w);
        ((ushort4*)d)[i] = o;
    }
}

__global__ __launch_bounds__(256)
void cast_w_k(const float* __restrict__ s0, const float* __restrict__ s1,
              const float* __restrict__ s2, const float* __restrict__ s3,
              ushort* __restrict__ d0, ushort* __restrict__ d1,
              ushort* __restrict__ d2, ushort* __restrict__ d3, int n4)
{
    const float* s = (blockIdx.y == 0) ? s0 : (blockIdx.y == 1) ? s1
                   : (blockIdx.y == 2) ? s2 : s3;
    ushort* d = (blockIdx.y == 0) ? d0 : (blockIdx.y == 1) ? d1
              : (blockIdx.y == 2) ? d2 : d3;
    for (int i = blockIdx.x * blockDim.x + threadIdx.x; i < n4;
         i += gridDim.x * blockDim.x) {
        float4 v = ((const float4*)s)[i];
        ushort4 o;
        o.x = f2bf(v.x); o.y = f2bf(v.y); o.z = f2bf(v.z); o.w = f2bf(v.w);
        ((ushort4*)d)[i] = o;
    }
}

// ---------------------------------------------------------------------------
// bf16 NT GEMM (unchanged from R3): global_load_lds 16B, dbuf LDS,
// counted vmcnt(8) across raw s_barrier, pre-swizzled global source.
// ---------------------------------------------------------------------------
template<int MODE>
__global__ __launch_bounds__(256)
void gemm_bf16(const ushort* __restrict__ A,
               const ushort* __restrict__ W0, const ushort* __restrict__ W1,
               const ushort* __restrict__ W2,
               ushort* __restrict__ D0, ushort* __restrict__ D1,
               ushort* __restrict__ D2,
               const float* __restrict__ bias, float* __restrict__ Fout)
{
    __shared__ __align__(16) ushort As[2][128 * 64];
    __shared__ __align__(16) ushort Bs[2][128 * 64];

    const int tid = threadIdx.x;
    const int w = tid >> 6, l = tid & 63;
    const int g = l >> 4, l15 = l & 15;
    const int wr = w >> 1, wc = w & 1;
    const int brow = blockIdx.x * 128, bcol = blockIdx.y * 128;

    const ushort* W = (MODE == 1) ? W0
                    : (blockIdx.z == 0 ? W0 : (blockIdx.z == 1 ? W1 : W2));
    ushort* Dst = (MODE == 1) ? (ushort*)0
                : (blockIdx.z == 0 ? D0 : (blockIdx.z == 1 ? D1 : D2));

    const int rsub = l >> 3;
    const int gc   = ((l & 7) ^ rsub) * 8;
    const size_t arow0 = (size_t)(brow + 32 * w + rsub) * DIM;
    const size_t brow0 = (size_t)(bcol + 32 * w + rsub) * DIM;

    auto STAGE = [&](int buf, int ktel) {
        #pragma unroll
        for (int i = 0; i < 4; ++i) {
            __builtin_amdgcn_global_load_lds(
                (const __attribute__((address_space(1))) void*)
                    &A[arow0 + (size_t)(8 * i) * DIM + ktel + gc],
                (__attribute__((address_space(3))) void*)
                    &As[buf][(32 * w + 8 * i) * 64], 16, 0, 0);
            __builtin_amdgcn_global_load_lds(
                (const __attribute__((address_space(1))) void*)
                    &W[brow0 + (size_t)(8 * i) * DIM + ktel + gc],
                (__attribute__((address_space(3))) void*)
                    &Bs[buf][(32 * w + 8 * i) * 64], 16, 0, 0);
        }
    };

    STAGE(0, 0);
    STAGE(1, 64);

    f32x4 acc[4][4] = {};

    for (int t = 0; t < 16; ++t) {
        const int cur = t & 1;
        if (t < 15) asm volatile("s_waitcnt vmcnt(8)" ::: "memory");
        else        asm volatile("s_waitcnt vmcnt(0)" ::: "memory");
        __builtin_amdgcn_s_barrier();
        __builtin_amdgcn_sched_barrier(0);

        #pragma unroll
        for (int kh = 0; kh < 2; ++kh) {
            bf16x8 af[4], bfr[4];
            #pragma unroll
            for (int mi = 0; mi < 4; ++mi) {
                int row = 64 * wr + 16 * mi + l15;
                af[mi] = *(const bf16x8*)&As[cur][row * 64 + (((4 * kh + g) ^ (row & 7)) * 8)];
            }
            #pragma unroll
            for (int nj = 0; nj < 4; ++nj) {
                int row = 64 * wc + 16 * nj + l15;
                bfr[nj] = *(const bf16x8*)&Bs[cur][row * 64 + (((4 * kh + g) ^ (row & 7)) * 8)];
            }
            __builtin_amdgcn_s_setprio(1);
            #pragma unroll
            for (int mi = 0; mi < 4; ++mi)
                #pragma unroll
                for (int nj = 0; nj < 4; ++nj)
                    acc[mi][nj] = __builtin_amdgcn_mfma_f32_16x16x32_bf16(
                        af[mi], bfr[nj], acc[mi][nj], 0, 0, 0);
            __builtin_amdgcn_s_setprio(0);
        }

        __builtin_amdgcn_sched_barrier(0);
        __builtin_amdgcn_s_barrier();
        if (t + 2 < 16) STAGE(cur, (t + 2) * 64);
    }

    if (MODE == 0) {
        const float osc = (blockIdx.z == 0) ? 0.125f : 1.0f;
        if (blockIdx.z == 2) {
            #pragma unroll
            for (int mi = 0; mi < 4; ++mi)
                #pragma unroll
                for (int nj = 0; nj < 4; ++nj)
                    #pragma unroll
                    for (int reg = 0; reg < 4; ++reg) {
                        int row = brow + 64 * wr + 16 * mi + 4 * g + reg;
                        int col = bcol + 64 * wc + 16 * nj + l15;
                        int b = row >> 11, t = row & (SEQ - 1);
                        int hh = col >> 6, hd = col & 63;
                        Dst[((size_t)(b * NH + hh) * HD + hd) * SEQ + t] =
                            f2bf(acc[mi][nj][reg]);
                    }
        } else {
            #pragma unroll
            for (int mi = 0; mi < 4; ++mi)
                #pragma unroll
                for (int nj = 0; nj < 4; ++nj)
                    #pragma unroll
                    for (int reg = 0; reg < 4; ++reg) {
                        int row = brow + 64 * wr + 16 * mi + 4 * g + reg;
                        int col = bcol + 64 * wc + 16 * nj + l15;
                        int b = row >> 11, t = row & (SEQ - 1);
                        int hh = col >> 6, hd = col & 63;
                        Dst[((size_t)(b * NH + hh) * SEQ + t) * HD + hd] =
                            f2bf(acc[mi][nj][reg] * osc);
                    }
        }
    } else {
        #pragma unroll
        for (int nj = 0; nj < 4; ++nj) {
            int col = bcol + 64 * wc + 16 * nj + l15;
            float bv = bias[col];
            #pragma unroll
            for (int mi = 0; mi < 4; ++mi)
                #pragma unroll
                for (int reg = 0; reg < 4; ++reg) {
                    int row = brow + 64 * wr + 16 * mi + 4 * g + reg;
                    Fout[(size_t)row * DIM + col] = acc[mi][nj][reg] + bv;
                }
        }
    }
}

// ---------------------------------------------------------------------------
// Flash attention v3: 1 wave per block, QBLK=32, grid 64x32 = 2048 blocks
// (= 8 waves/CU, ALL resident -> duration = longest block, no tail).
// No LDS staging, no barriers: K/V^T/Q MFMA fragments are contiguous 16B
// per-lane row segments -> loaded directly from global (L2-resident).
// K software-pipelined in regs (double buffer via duplicated body).
// Softmax in-register, tree reductions; defer-max THR=8; cvt_pk+shfl P.
// ---------------------------------------------------------------------------
__global__ __launch_bounds__(64, 2)
void attn_mfma3(const ushort* __restrict__ q, const ushort* __restrict__ k,
                const ushort* __restrict__ vt, ushort* __restrict__ ctx)
{
    __shared__ __align__(16) ushort Ob[32 * 64];   // output bounce only (4KB)

    const int l = threadIdx.x;
    const int l31 = l & 31, h = l >> 5;
    const int qt = blockIdx.x;            // 32-row q tile, 0..63
    const int bh = blockIdx.y;
    const int qlo = qt * 32;
    const int last = qt >> 1;             // last 64-wide kv tile index
    const float LOG2E = 1.44269504f;

    const ushort* Qg = q  + (size_t)bh * SEQ * HD;
    const ushort* Kg = k  + (size_t)bh * SEQ * HD;
    const ushort* Vg = vt + (size_t)bh * HD * SEQ;

    // Q B-frags (lane: q-row = qlo+l31, k-slice 16s+8h)
    bf16x8 qf[4];
    #pragma unroll
    for (int s = 0; s < 4; ++s)
        qf[s] = *(const bf16x8*)&Qg[(size_t)(qlo + l31) * HD + 16 * s + 8 * h];

    f32x16 o[2] = {};
    float m = -3.0e38f, lsum = 0.f;

    bf16x8 kfA[8], kfB[8];
    #pragma unroll
    for (int s = 0; s < 4; ++s)
        #pragma unroll
        for (int f = 0; f < 2; ++f)
            kfA[2 * s + f] = *(const bf16x8*)
                &Kg[(size_t)(32 * f + l31) * HD + 16 * s + 8 * h];

    auto body = [&](bf16x8 (&kc)[8], bf16x8 (&kn)[8], int kt) {
        const int kvb = 64 * kt;

        // V^T B-frags for current tile (latency hides under QK + softmax)
        bf16x8 vf[8];
        #pragma unroll
        for (int s4 = 0; s4 < 4; ++s4)
            #pragma unroll
            for (int dt = 0; dt < 2; ++dt)
                vf[2 * s4 + dt] = *(const bf16x8*)
                    &Vg[(size_t)(32 * dt + l31) * SEQ + kvb + 16 * s4 + 8 * h];

        // S^T = K · Q^T
        f32x16 st[2] = {};
        #pragma unroll
        for (int s = 0; s < 4; ++s)
            #pragma unroll
            for (int f = 0; f < 2; ++f)
                st[f] = __builtin_amdgcn_mfma_f32_32x32x16_bf16(
                    kc[2 * s + f], qf[s], st[f], 0, 0, 0);

        // prefetch next K tile (latency hides under softmax + PV)
        if (kt < last) {
            #pragma unroll
            for (int s = 0; s < 4; ++s)
                #pragma unroll
                for (int f = 0; f < 2; ++f)
                    kn[2 * s + f] = *(const bf16x8*)
                        &Kg[(size_t)(kvb + 64 + 32 * f + l31) * HD + 16 * s + 8 * h];
        }

        // causal mask (only the last tile can straddle the diagonal)
        const int qg = qlo + l31;
        if (kvb + 63 > qlo) {
            #pragma unroll
            for (int f = 0; f < 2; ++f)
                #pragma unroll
                for (int r = 0; r < 16; ++r) {
                    int kvg = kvb + 32 * f + (r & 3) + 8 * (r >> 2) + 4 * h;
                    if (kvg > qg) st[f][r] = -INFINITY;
                }
        }

        // row max, tree
        float mx[8];
        #pragma unroll
        for (int i2 = 0; i2 < 8; ++i2) {
            const int f = i2 >> 2, rb = 4 * (i2 & 3);
            mx[i2] = fmaxf(fmaxf(st[f][rb], st[f][rb + 1]),
                           fmaxf(st[f][rb + 2], st[f][rb + 3]));
        }
        float tmax = fmaxf(fmaxf(fmaxf(mx[0], mx[1]), fmaxf(mx[2], mx[3])),
                           fmaxf(fmaxf(mx[4], mx[5]), fmaxf(mx[6], mx[7])));
        tmax = fmaxf(tmax, __shfl_xor(tmax, 32));
        float ty = fmaxf(tmax * LOG2E, -3.0e38f);

        if (!__all(ty - m <= 8.0f)) {            // T13 defer-max
            float mn = fmaxf(m, ty);
            float sc = exp2f(m - mn);
            lsum *= sc;
            #pragma unroll
            for (int dt = 0; dt < 2; ++dt)
                #pragma unroll
                for (int r = 0; r < 16; ++r) o[dt][r] *= sc;
            m = mn;
        }

        // exp + partial sums (4-way interleave breaks the add chain)
        float ls0 = 0.f, ls1 = 0.f, ls2 = 0.f, ls3 = 0.f;
        #pragma unroll
        for (int f = 0; f < 2; ++f)
            #pragma unroll
            for (int r = 0; r < 16; ++r) {
                float pv = exp2f(fmaf(st[f][r], LOG2E, -m));
                st[f][r] = pv;
                if ((r & 3) == 0) ls0 += pv;
                else if ((r & 3) == 1) ls1 += pv;
                else if ((r & 3) == 2) ls2 += pv;
                else ls3 += pv;
            }
        lsum += (ls0 + ls1) + (ls2 + ls3);

        // P -> PA frags (cvt_pk + half-wave exchange), PV MFMAs
        #pragma unroll
        for (int s4 = 0; s4 < 4; ++s4) {
            const int f = s4 >> 1, rb2 = 8 * (s4 & 1);
            unsigned Aa = cvtpk_bf16(st[f][rb2 + 0], st[f][rb2 + 1]);
            unsigned Bb = cvtpk_bf16(st[f][rb2 + 2], st[f][rb2 + 3]);
            unsigned Cc = cvtpk_bf16(st[f][rb2 + 4], st[f][rb2 + 5]);
            unsigned Dd = cvtpk_bf16(st[f][rb2 + 6], st[f][rb2 + 7]);
            unsigned Ax = (unsigned)__shfl_xor((int)Aa, 32);
            unsigned Bx = (unsigned)__shfl_xor((int)Bb, 32);
            unsigned Cx = (unsigned)__shfl_xor((int)Cc, 32);
            unsigned Dx = (unsigned)__shfl_xor((int)Dd, 32);
            union { unsigned wv[4]; bf16x8 v; } pu;
            pu.wv[0] = h ? Cx : Aa;
            pu.wv[1] = h ? Dx : Bb;
            pu.wv[2] = h ? Cc : Ax;
            pu.wv[3] = h ? Dd : Bx;
            #pragma unroll
            for (int dt = 0; dt < 2; ++dt)
                o[dt] = __builtin_amdgcn_mfma_f32_32x32x16_bf16(
                    vf[2 * s4 + dt], pu.v, o[dt], 0, 0, 0);
        }
    };

    int kt = 0;
    while (true) {
        body(kfA, kfB, kt);
        if (++kt > last) break;
        body(kfB, kfA, kt);
        if (++kt > last) break;
    }

    // normalize + write (coalesce via 4KB LDS bounce)
    float lt = lsum + __shfl_xor(lsum, 32);
    float inv = 1.0f / lt;

    #pragma unroll
    for (int dt = 0; dt < 2; ++dt)
        #pragma unroll
        for (int r = 0; r < 16; r += 2) {
            int d = 32 * dt + (r & 3) + 8 * (r >> 2) + 4 * h;
            unsigned wrd = cvtpk_bf16(o[dt][r] * inv, o[dt][r + 1] * inv);
            *(unsigned*)&Ob[l31 * 64 + (((d >> 3) ^ (l31 & 7)) * 8) + (d & 7)] = wrd;
        }
    asm volatile("s_waitcnt lgkmcnt(0)" ::: "memory");
    __builtin_amdgcn_sched_barrier(0);

    ushort* Cg = ctx + (size_t)bh * SEQ * HD + (size_t)qlo * HD;
    #pragma unroll
    for (int i = 0; i < 4; ++i) {
        int qq = l >> 1, c = (l & 1) * 4 + i;
        int4 vvv = *(const int4*)&Ob[qq * 64 + ((c ^ (qq & 7)) * 8)];
        *(int4*)&Cg[qq * 64 + c * 8] = vvv;
    }
}

// ---------------------------------------------------------------------------
extern "C" void kernel_launch(void* const* d_in, const int* in_sizes, int n_in,
                              void* d_out, int out_size, void* d_ws, size_t ws_size,
                              hipStream_t stream)
{
    (void)in_sizes; (void)n_in; (void)out_size; (void)ws_size;
    const float* x  = (const float*)d_in[0];
    const float* Wq = (const float*)d_in[1];
    const float* Wk = (const float*)d_in[2];
    const float* Wv = (const float*)d_in[3];
    const float* Wo = (const float*)d_in[4];
    const float* bo = (const float*)d_in[5];
    float* out = (float*)d_out;

    ushort* wsu  = (ushort*)d_ws;
    ushort* xb   = wsu;                      // 4M
    ushort* wqb  = wsu + 4194304;            // 1M each
    ushort* wkb  = wsu + 5242880;
    ushort* wvb  = wsu + 6291456;
    ushort* wob  = wsu + 7340032;
    ushort* qbuf = wsu + 8388608;            // 4M, [B,H,T,HD], pre-scaled 0.125
    ushort* kbuf = wsu + 12582912;           // 4M, [B,H,T,HD]
    ushort* vtb  = wsu + 16777216;           // 4M, [B,H,HD,T]  (V transposed)
    ushort* ctxb = wsu + 20971520;           // 4M, flat == [B*T, D]

    cast_x_k<<<2048, 256, 0, stream>>>(x, xb, MTOT * DIM / 4);
    cast_w_k<<<dim3(512, 4), 256, 0, stream>>>(Wq, Wk, Wv, Wo,
                                               wqb, wkb, wvb, wob, DIM * DIM / 4);

    dim3 gqkv(MTOT / 128, DIM / 128, 3);
    gemm_bf16<0><<<gqkv, 256, 0, stream>>>(xb, wqb, wkb, wvb,
                                           qbuf, kbuf, vtb, nullptr, nullptr);

    dim3 ga(SEQ / 32, BATCH * NH);
    attn_mfma3<<<ga, 64, 0, stream>>>(qbuf, kbuf, vtb, ctxb);

    dim3 go(MTOT / 128, DIM / 128, 1);
    gemm_bf16<1><<<go, 256, 0, stream>>>(ctxb, wob, nullptr, nullptr,
                                         nullptr, nullptr, nullptr, bo, out);
}

// Round 6
// 124.062 us; speedup vs baseline: 1.4939x; 1.4939x over previous
//
#include <hip/hip_runtime.h>
#include <math.h>

#define BATCH 2
#define SEQ   2048
#define DIM   1024
#define NH    16
#define HD    64
#define MTOT  4096

typedef __attribute__((ext_vector_type(8)))  short bf16x8;
typedef __attribute__((ext_vector_type(4)))  float f32x4;
typedef __attribute__((ext_vector_type(16))) float f32x16;

__device__ __forceinline__ ushort f2bf(float f) {
    union { float f; unsigned u; } v; v.f = f;
    unsigned r = v.u + 0x7fffu + ((v.u >> 16) & 1u);
    return (ushort)(r >> 16);
}

__device__ __forceinline__ unsigned cvtpk_bf16(float lo, float hi) {
    unsigned r;
    asm("v_cvt_pk_bf16_f32 %0, %1, %2" : "=v"(r) : "v"(lo), "v"(hi));
    return r;
}

// ---------------------------------------------------------------------------
// casts
// ---------------------------------------------------------------------------
__global__ __launch_bounds__(256)
void cast_x_k(const float* __restrict__ s, ushort* __restrict__ d, int n4)
{
    for (int i = blockIdx.x * blockDim.x + threadIdx.x; i < n4;
         i += gridDim.x * blockDim.x) {
        float4 v = ((const float4*)s)[i];
        ushort4 o;
        o.x = f2bf(v.x); o.y = f2bf(v.y); o.z = f2bf(v.z); o.w = f2bf(v.w);
        ((ushort4*)d)[i] = o;
    }
}

__global__ __launch_bounds__(256)
void cast_w_k(const float* __restrict__ s0, const float* __restrict__ s1,
              const float* __restrict__ s2, const float* __restrict__ s3,
              ushort* __restrict__ d0, ushort* __restrict__ d1,
              ushort* __restrict__ d2, ushort* __restrict__ d3, int n4)
{
    const float* s = (blockIdx.y == 0) ? s0 : (blockIdx.y == 1) ? s1
                   : (blockIdx.y == 2) ? s2 : s3;
    ushort* d = (blockIdx.y == 0) ? d0 : (blockIdx.y == 1) ? d1
              : (blockIdx.y == 2) ? d2 : d3;
    for (int i = blockIdx.x * blockDim.x + threadIdx.x; i < n4;
         i += gridDim.x * blockDim.x) {
        float4 v = ((const float4*)s)[i];
        ushort4 o;
        o.x = f2bf(v.x); o.y = f2bf(v.y); o.z = f2bf(v.z); o.w = f2bf(v.w);
        ((ushort4*)d)[i] = o;
    }
}

// ---------------------------------------------------------------------------
// bf16 NT GEMM (R3 pipeline). MODE 0 scatters into FRAGMENT-MAJOR layouts:
//   z=0 Q*0.125, z=1 K:  chunk = ((t>>5)*8 + (d>>3))*32 + (t&31), elem d&7
//   z=2 V^T:             chunk = (t>>3)*64 + d,                  elem t&7
// so attention's per-lane 16B fragment loads are lane-contiguous.
// MODE 1: fp32 [M,N] + bias.
// ---------------------------------------------------------------------------
template<int MODE>
__global__ __launch_bounds__(256)
void gemm_bf16(const ushort* __restrict__ A,
               const ushort* __restrict__ W0, const ushort* __restrict__ W1,
               const ushort* __restrict__ W2,
               ushort* __restrict__ D0, ushort* __restrict__ D1,
               ushort* __restrict__ D2,
               const float* __restrict__ bias, float* __restrict__ Fout)
{
    __shared__ __align__(16) ushort As[2][128 * 64];
    __shared__ __align__(16) ushort Bs[2][128 * 64];

    const int tid = threadIdx.x;
    const int w = tid >> 6, l = tid & 63;
    const int g = l >> 4, l15 = l & 15;
    const int wr = w >> 1, wc = w & 1;
    const int brow = blockIdx.x * 128, bcol = blockIdx.y * 128;

    const ushort* W = (MODE == 1) ? W0
                    : (blockIdx.z == 0 ? W0 : (blockIdx.z == 1 ? W1 : W2));
    ushort* Dst = (MODE == 1) ? (ushort*)0
                : (blockIdx.z == 0 ? D0 : (blockIdx.z == 1 ? D1 : D2));

    const int rsub = l >> 3;
    const int gc   = ((l & 7) ^ rsub) * 8;
    const size_t arow0 = (size_t)(brow + 32 * w + rsub) * DIM;
    const size_t brow0 = (size_t)(bcol + 32 * w + rsub) * DIM;

    auto STAGE = [&](int buf, int ktel) {
        #pragma unroll
        for (int i = 0; i < 4; ++i) {
            __builtin_amdgcn_global_load_lds(
                (const __attribute__((address_space(1))) void*)
                    &A[arow0 + (size_t)(8 * i) * DIM + ktel + gc],
                (__attribute__((address_space(3))) void*)
                    &As[buf][(32 * w + 8 * i) * 64], 16, 0, 0);
            __builtin_amdgcn_global_load_lds(
                (const __attribute__((address_space(1))) void*)
                    &W[brow0 + (size_t)(8 * i) * DIM + ktel + gc],
                (__attribute__((address_space(3))) void*)
                    &Bs[buf][(32 * w + 8 * i) * 64], 16, 0, 0);
        }
    };

    STAGE(0, 0);
    STAGE(1, 64);

    f32x4 acc[4][4] = {};

    for (int t = 0; t < 16; ++t) {
        const int cur = t & 1;
        if (t < 15) asm volatile("s_waitcnt vmcnt(8)" ::: "memory");
        else        asm volatile("s_waitcnt vmcnt(0)" ::: "memory");
        __builtin_amdgcn_s_barrier();
        __builtin_amdgcn_sched_barrier(0);

        #pragma unroll
        for (int kh = 0; kh < 2; ++kh) {
            bf16x8 af[4], bfr[4];
            #pragma unroll
            for (int mi = 0; mi < 4; ++mi) {
                int row = 64 * wr + 16 * mi + l15;
                af[mi] = *(const bf16x8*)&As[cur][row * 64 + (((4 * kh + g) ^ (row & 7)) * 8)];
            }
            #pragma unroll
            for (int nj = 0; nj < 4; ++nj) {
                int row = 64 * wc + 16 * nj + l15;
                bfr[nj] = *(const bf16x8*)&Bs[cur][row * 64 + (((4 * kh + g) ^ (row & 7)) * 8)];
            }
            __builtin_amdgcn_s_setprio(1);
            #pragma unroll
            for (int mi = 0; mi < 4; ++mi)
                #pragma unroll
                for (int nj = 0; nj < 4; ++nj)
                    acc[mi][nj] = __builtin_amdgcn_mfma_f32_16x16x32_bf16(
                        af[mi], bfr[nj], acc[mi][nj], 0, 0, 0);
            __builtin_amdgcn_s_setprio(0);
        }

        __builtin_amdgcn_sched_barrier(0);
        __builtin_amdgcn_s_barrier();
        if (t + 2 < 16) STAGE(cur, (t + 2) * 64);
    }

    if (MODE == 0) {
        const float osc = (blockIdx.z == 0) ? 0.125f : 1.0f;
        if (blockIdx.z == 2) {
            // V^T fragment-major: chunk = (t>>3)*64 + d, elem t&7
            #pragma unroll
            for (int mi = 0; mi < 4; ++mi)
                #pragma unroll
                for (int nj = 0; nj < 4; ++nj)
                    #pragma unroll
                    for (int reg = 0; reg < 4; ++reg) {
                        int row = brow + 64 * wr + 16 * mi + 4 * g + reg;
                        int col = bcol + 64 * wc + 16 * nj + l15;
                        int b = row >> 11, t = row & (SEQ - 1);
                        int hh = col >> 6, hd = col & 63;
                        Dst[(size_t)(b * NH + hh) * SEQ * HD
                            + ((size_t)(t >> 3) * 64 + hd) * 8 + (t & 7)] =
                            f2bf(acc[mi][nj][reg]);
                    }
        } else {
            // Q/K fragment-major: chunk = ((t>>5)*8 + (d>>3))*32 + (t&31), elem d&7
            #pragma unroll
            for (int mi = 0; mi < 4; ++mi)
                #pragma unroll
                for (int nj = 0; nj < 4; ++nj)
                    #pragma unroll
                    for (int reg = 0; reg < 4; ++reg) {
                        int row = brow + 64 * wr + 16 * mi + 4 * g + reg;
                        int col = bcol + 64 * wc + 16 * nj + l15;
                        int b = row >> 11, t = row & (SEQ - 1);
                        int hh = col >> 6, hd = col & 63;
                        Dst[(size_t)(b * NH + hh) * SEQ * HD
                            + (((size_t)(t >> 5) * 8 + (hd >> 3)) * 32 + (t & 31)) * 8
                            + (hd & 7)] = f2bf(acc[mi][nj][reg] * osc);
                    }
        }
    } else {
        #pragma unroll
        for (int nj = 0; nj < 4; ++nj) {
            int col = bcol + 64 * wc + 16 * nj + l15;
            float bv = bias[col];
            #pragma unroll
            for (int mi = 0; mi < 4; ++mi)
                #pragma unroll
                for (int reg = 0; reg < 4; ++reg) {
                    int row = brow + 64 * wr + 16 * mi + 4 * g + reg;
                    Fout[(size_t)row * DIM + col] = acc[mi][nj][reg] + bv;
                }
        }
    }
}

// ---------------------------------------------------------------------------
// Flash attention v4: 1 wave/block, QBLK=32, zero barriers, all fragment
// loads COALESCED (fragment-major global layouts). qt de-aliased across CUs
// via (x + 7*bh) & 63 so per-CU work is mixed-size.
// ---------------------------------------------------------------------------
__global__ __launch_bounds__(64, 2)
void attn_mfma4(const ushort* __restrict__ q, const ushort* __restrict__ k,
                const ushort* __restrict__ vt, ushort* __restrict__ ctx)
{
    __shared__ __align__(16) ushort Ob[32 * 64];   // output bounce only (4KB)

    const int l = threadIdx.x;
    const int l31 = l & 31, h = l >> 5;
    const int bh = blockIdx.y;
    const int qt = ((int)blockIdx.x + 7 * bh) & 63;   // de-alias CU load
    const int qlo = qt * 32;
    const int last = qt >> 1;
    const float LOG2E = 1.44269504f;

    const ushort* Qg = q  + (size_t)bh * SEQ * HD;
    const ushort* Kg = k  + (size_t)bh * SEQ * HD;
    const ushort* Vg = vt + (size_t)bh * SEQ * HD;

    // Q B-frags: coalesced chunk ((qt*8 + 2s+h)*32 + l31)
    bf16x8 qf[4];
    #pragma unroll
    for (int s = 0; s < 4; ++s)
        qf[s] = *(const bf16x8*)&Qg[(((size_t)qt * 8 + 2 * s + h) * 32 + l31) * 8];

    f32x16 o[2] = {};
    float m = -3.0e38f, lsum = 0.f;

    bf16x8 kfA[8], kfB[8];
    #pragma unroll
    for (int s = 0; s < 4; ++s)
        #pragma unroll
        for (int f = 0; f < 2; ++f)
            kfA[2 * s + f] = *(const bf16x8*)
                &Kg[(((size_t)f * 8 + 2 * s + h) * 32 + l31) * 8];

    auto body = [&](bf16x8 (&kc)[8], bf16x8 (&kn)[8], int kt) {
        const int kvb = 64 * kt;

        // V^T frags, coalesced: chunk ((8kt + 2s4 + h)*64 + 32dt + l31)
        bf16x8 vf[8];
        #pragma unroll
        for (int s4 = 0; s4 < 4; ++s4)
            #pragma unroll
            for (int dt = 0; dt < 2; ++dt)
                vf[2 * s4 + dt] = *(const bf16x8*)
                    &Vg[(((size_t)(8 * kt + 2 * s4 + h)) * 64 + 32 * dt + l31) * 8];

        // S^T = K · Q^T
        f32x16 st[2] = {};
        #pragma unroll
        for (int s = 0; s < 4; ++s)
            #pragma unroll
            for (int f = 0; f < 2; ++f)
                st[f] = __builtin_amdgcn_mfma_f32_32x32x16_bf16(
                    kc[2 * s + f], qf[s], st[f], 0, 0, 0);

        // prefetch next K tile
        if (kt < last) {
            #pragma unroll
            for (int s = 0; s < 4; ++s)
                #pragma unroll
                for (int f = 0; f < 2; ++f)
                    kn[2 * s + f] = *(const bf16x8*)
                        &Kg[(((size_t)(2 * kt + 2 + f) * 8 + 2 * s + h) * 32 + l31) * 8];
        }

        // causal mask (only straddling tile)
        const int qg = qlo + l31;
        if (kvb + 63 > qlo) {
            #pragma unroll
            for (int f = 0; f < 2; ++f)
                #pragma unroll
                for (int r = 0; r < 16; ++r) {
                    int kvg = kvb + 32 * f + (r & 3) + 8 * (r >> 2) + 4 * h;
                    if (kvg > qg) st[f][r] = -INFINITY;
                }
        }

        // row max, tree
        float mx[8];
        #pragma unroll
        for (int i2 = 0; i2 < 8; ++i2) {
            const int f = i2 >> 2, rb = 4 * (i2 & 3);
            mx[i2] = fmaxf(fmaxf(st[f][rb], st[f][rb + 1]),
                           fmaxf(st[f][rb + 2], st[f][rb + 3]));
        }
        float tmax = fmaxf(fmaxf(fmaxf(mx[0], mx[1]), fmaxf(mx[2], mx[3])),
                           fmaxf(fmaxf(mx[4], mx[5]), fmaxf(mx[6], mx[7])));
        tmax = fmaxf(tmax, __shfl_xor(tmax, 32));
        float ty = fmaxf(tmax * LOG2E, -3.0e38f);

        if (!__all(ty - m <= 8.0f)) {            // T13 defer-max
            float mn = fmaxf(m, ty);
            float sc = exp2f(m - mn);
            lsum *= sc;
            #pragma unroll
            for (int dt = 0; dt < 2; ++dt)
                #pragma unroll
                for (int r = 0; r < 16; ++r) o[dt][r] *= sc;
            m = mn;
        }

        // exp + partial sums
        float ls0 = 0.f, ls1 = 0.f, ls2 = 0.f, ls3 = 0.f;
        #pragma unroll
        for (int f = 0; f < 2; ++f)
            #pragma unroll
            for (int r = 0; r < 16; ++r) {
                float pv = exp2f(fmaf(st[f][r], LOG2E, -m));
                st[f][r] = pv;
                if ((r & 3) == 0) ls0 += pv;
                else if ((r & 3) == 1) ls1 += pv;
                else if ((r & 3) == 2) ls2 += pv;
                else ls3 += pv;
            }
        lsum += (ls0 + ls1) + (ls2 + ls3);

        // P -> PA frags (cvt_pk + half-wave exchange), PV MFMAs
        #pragma unroll
        for (int s4 = 0; s4 < 4; ++s4) {
            const int f = s4 >> 1, rb2 = 8 * (s4 & 1);
            unsigned Aa = cvtpk_bf16(st[f][rb2 + 0], st[f][rb2 + 1]);
            unsigned Bb = cvtpk_bf16(st[f][rb2 + 2], st[f][rb2 + 3]);
            unsigned Cc = cvtpk_bf16(st[f][rb2 + 4], st[f][rb2 + 5]);
            unsigned Dd = cvtpk_bf16(st[f][rb2 + 6], st[f][rb2 + 7]);
            unsigned Ax = (unsigned)__shfl_xor((int)Aa, 32);
            unsigned Bx = (unsigned)__shfl_xor((int)Bb, 32);
            unsigned Cx = (unsigned)__shfl_xor((int)Cc, 32);
            unsigned Dx = (unsigned)__shfl_xor((int)Dd, 32);
            union { unsigned wv[4]; bf16x8 v; } pu;
            pu.wv[0] = h ? Cx : Aa;
            pu.wv[1] = h ? Dx : Bb;
            pu.wv[2] = h ? Cc : Ax;
            pu.wv[3] = h ? Dd : Bx;
            #pragma unroll
            for (int dt = 0; dt < 2; ++dt)
                o[dt] = __builtin_amdgcn_mfma_f32_32x32x16_bf16(
                    vf[2 * s4 + dt], pu.v, o[dt], 0, 0, 0);
        }
    };

    int kt = 0;
    while (true) {
        body(kfA, kfB, kt);
        if (++kt > last) break;
        body(kfB, kfA, kt);
        if (++kt > last) break;
    }

    // normalize + write (coalesce via 4KB LDS bounce)
    float lt = lsum + __shfl_xor(lsum, 32);
    float inv = 1.0f / lt;

    #pragma unroll
    for (int dt = 0; dt < 2; ++dt)
        #pragma unroll
        for (int r = 0; r < 16; r += 2) {
            int d = 32 * dt + (r & 3) + 8 * (r >> 2) + 4 * h;
            unsigned wrd = cvtpk_bf16(o[dt][r] * inv, o[dt][r + 1] * inv);
            *(unsigned*)&Ob[l31 * 64 + (((d >> 3) ^ (l31 & 7)) * 8) + (d & 7)] = wrd;
        }
    asm volatile("s_waitcnt lgkmcnt(0)" ::: "memory");
    __builtin_amdgcn_sched_barrier(0);

    ushort* Cg = ctx + (size_t)bh * SEQ * HD + (size_t)qlo * HD;
    #pragma unroll
    for (int i = 0; i < 4; ++i) {
        int qq = l >> 1, c = (l & 1) * 4 + i;
        int4 vvv = *(const int4*)&Ob[qq * 64 + ((c ^ (qq & 7)) * 8)];
        *(int4*)&Cg[qq * 64 + c * 8] = vvv;
    }
}

// ---------------------------------------------------------------------------
extern "C" void kernel_launch(void* const* d_in, const int* in_sizes, int n_in,
                              void* d_out, int out_size, void* d_ws, size_t ws_size,
                              hipStream_t stream)
{
    (void)in_sizes; (void)n_in; (void)out_size; (void)ws_size;
    const float* x  = (const float*)d_in[0];
    const float* Wq = (const float*)d_in[1];
    const float* Wk = (const float*)d_in[2];
    const float* Wv = (const float*)d_in[3];
    const float* Wo = (const float*)d_in[4];
    const float* bo = (const float*)d_in[5];
    float* out = (float*)d_out;

    ushort* wsu  = (ushort*)d_ws;
    ushort* xb   = wsu;                      // 4M
    ushort* wqb  = wsu + 4194304;            // 1M each
    ushort* wkb  = wsu + 5242880;
    ushort* wvb  = wsu + 6291456;
    ushort* wob  = wsu + 7340032;
    ushort* qbuf = wsu + 8388608;            // 4M, Q fragment-major, *0.125
    ushort* kbuf = wsu + 12582912;           // 4M, K fragment-major
    ushort* vtb  = wsu + 16777216;           // 4M, V^T fragment-major
    ushort* ctxb = wsu + 20971520;           // 4M, flat == [B*T, D]

    cast_x_k<<<2048, 256, 0, stream>>>(x, xb, MTOT * DIM / 4);
    cast_w_k<<<dim3(512, 4), 256, 0, stream>>>(Wq, Wk, Wv, Wo,
                                               wqb, wkb, wvb, wob, DIM * DIM / 4);

    dim3 gqkv(MTOT / 128, DIM / 128, 3);
    gemm_bf16<0><<<gqkv, 256, 0, stream>>>(xb, wqb, wkb, wvb,
                                           qbuf, kbuf, vtb, nullptr, nullptr);

    dim3 ga(SEQ / 32, BATCH * NH);
    attn_mfma4<<<ga, 64, 0, stream>>>(qbuf, kbuf, vtb, ctxb);

    dim3 go(MTOT / 128, DIM / 128, 1);
    gemm_bf16<1><<<go, 256, 0, stream>>>(ctxb, wob, nullptr, nullptr,
                                         nullptr, nullptr, nullptr, bo, out);
}

// Round 7
// 116.345 us; speedup vs baseline: 1.5929x; 1.0663x over previous
//
#include <hip/hip_runtime.h>
#include <math.h>

#define BATCH 2
#define SEQ   2048
#define DIM   1024
#define NH    16
#define HD    64
#define MTOT  4096

typedef __attribute__((ext_vector_type(8)))  short bf16x8;
typedef __attribute__((ext_vector_type(4)))  float f32x4;
typedef __attribute__((ext_vector_type(16))) float f32x16;

__device__ __forceinline__ ushort f2bf(float f) {
    union { float f; unsigned u; } v; v.f = f;
    unsigned r = v.u + 0x7fffu + ((v.u >> 16) & 1u);
    return (ushort)(r >> 16);
}

__device__ __forceinline__ unsigned cvtpk_bf16(float lo, float hi) {
    unsigned r;
    asm("v_cvt_pk_bf16_f32 %0, %1, %2" : "=v"(r) : "v"(lo), "v"(hi));
    return r;
}

// ---------------------------------------------------------------------------
// fused cast: z=0 x (4M f4), z=1..4 Wq/Wk/Wv/Wo (1M f4 each)
// ---------------------------------------------------------------------------
__global__ __launch_bounds__(256)
void cast_all(const float* __restrict__ x,
              const float* __restrict__ Wq, const float* __restrict__ Wk,
              const float* __restrict__ Wv, const float* __restrict__ Wo,
              ushort* __restrict__ xb,
              ushort* __restrict__ wqb, ushort* __restrict__ wkb,
              ushort* __restrict__ wvb, ushort* __restrict__ wob)
{
    const int z = blockIdx.y;
    const float* s; ushort* d; int n4;
    if (z == 0)      { s = x;  d = xb;  n4 = MTOT * DIM / 4; }
    else if (z == 1) { s = Wq; d = wqb; n4 = DIM * DIM / 4; }
    else if (z == 2) { s = Wk; d = wkb; n4 = DIM * DIM / 4; }
    else if (z == 3) { s = Wv; d = wvb; n4 = DIM * DIM / 4; }
    else             { s = Wo; d = wob; n4 = DIM * DIM / 4; }
    for (int i = blockIdx.x * blockDim.x + threadIdx.x; i < n4;
         i += gridDim.x * blockDim.x) {
        float4 v = ((const float4*)s)[i];
        ushort4 o;
        o.x = f2bf(v.x); o.y = f2bf(v.y); o.z = f2bf(v.z); o.w = f2bf(v.w);
        ((ushort4*)d)[i] = o;
    }
}

// ---------------------------------------------------------------------------
// bf16 NT GEMM (R3 pipeline). MODE 0 scatters into FRAGMENT-MAJOR layouts:
//   z=0 Q*0.125, z=1 K:  chunk = ((t>>5)*8 + (d>>3))*32 + (t&31), elem d&7
//   z=2 V^T:             chunk = (t>>3)*64 + d,                  elem t&7
// MODE 1: fp32 [M,N] + bias.
// ---------------------------------------------------------------------------
template<int MODE>
__global__ __launch_bounds__(256)
void gemm_bf16(const ushort* __restrict__ A,
               const ushort* __restrict__ W0, const ushort* __restrict__ W1,
               const ushort* __restrict__ W2,
               ushort* __restrict__ D0, ushort* __restrict__ D1,
               ushort* __restrict__ D2,
               const float* __restrict__ bias, float* __restrict__ Fout)
{
    __shared__ __align__(16) ushort As[2][128 * 64];
    __shared__ __align__(16) ushort Bs[2][128 * 64];

    const int tid = threadIdx.x;
    const int w = tid >> 6, l = tid & 63;
    const int g = l >> 4, l15 = l & 15;
    const int wr = w >> 1, wc = w & 1;
    const int brow = blockIdx.x * 128, bcol = blockIdx.y * 128;

    const ushort* W = (MODE == 1) ? W0
                    : (blockIdx.z == 0 ? W0 : (blockIdx.z == 1 ? W1 : W2));
    ushort* Dst = (MODE == 1) ? (ushort*)0
                : (blockIdx.z == 0 ? D0 : (blockIdx.z == 1 ? D1 : D2));

    const int rsub = l >> 3;
    const int gc   = ((l & 7) ^ rsub) * 8;
    const size_t arow0 = (size_t)(brow + 32 * w + rsub) * DIM;
    const size_t brow0 = (size_t)(bcol + 32 * w + rsub) * DIM;

    auto STAGE = [&](int buf, int ktel) {
        #pragma unroll
        for (int i = 0; i < 4; ++i) {
            __builtin_amdgcn_global_load_lds(
                (const __attribute__((address_space(1))) void*)
                    &A[arow0 + (size_t)(8 * i) * DIM + ktel + gc],
                (__attribute__((address_space(3))) void*)
                    &As[buf][(32 * w + 8 * i) * 64], 16, 0, 0);
            __builtin_amdgcn_global_load_lds(
                (const __attribute__((address_space(1))) void*)
                    &W[brow0 + (size_t)(8 * i) * DIM + ktel + gc],
                (__attribute__((address_space(3))) void*)
                    &Bs[buf][(32 * w + 8 * i) * 64], 16, 0, 0);
        }
    };

    STAGE(0, 0);
    STAGE(1, 64);

    f32x4 acc[4][4] = {};

    for (int t = 0; t < 16; ++t) {
        const int cur = t & 1;
        if (t < 15) asm volatile("s_waitcnt vmcnt(8)" ::: "memory");
        else        asm volatile("s_waitcnt vmcnt(0)" ::: "memory");
        __builtin_amdgcn_s_barrier();
        __builtin_amdgcn_sched_barrier(0);

        #pragma unroll
        for (int kh = 0; kh < 2; ++kh) {
            bf16x8 af[4], bfr[4];
            #pragma unroll
            for (int mi = 0; mi < 4; ++mi) {
                int row = 64 * wr + 16 * mi + l15;
                af[mi] = *(const bf16x8*)&As[cur][row * 64 + (((4 * kh + g) ^ (row & 7)) * 8)];
            }
            #pragma unroll
            for (int nj = 0; nj < 4; ++nj) {
                int row = 64 * wc + 16 * nj + l15;
                bfr[nj] = *(const bf16x8*)&Bs[cur][row * 64 + (((4 * kh + g) ^ (row & 7)) * 8)];
            }
            __builtin_amdgcn_s_setprio(1);
            #pragma unroll
            for (int mi = 0; mi < 4; ++mi)
                #pragma unroll
                for (int nj = 0; nj < 4; ++nj)
                    acc[mi][nj] = __builtin_amdgcn_mfma_f32_16x16x32_bf16(
                        af[mi], bfr[nj], acc[mi][nj], 0, 0, 0);
            __builtin_amdgcn_s_setprio(0);
        }

        __builtin_amdgcn_sched_barrier(0);
        __builtin_amdgcn_s_barrier();
        if (t + 2 < 16) STAGE(cur, (t + 2) * 64);
    }

    if (MODE == 0) {
        const float osc = (blockIdx.z == 0) ? 0.125f : 1.0f;
        if (blockIdx.z == 2) {
            #pragma unroll
            for (int mi = 0; mi < 4; ++mi)
                #pragma unroll
                for (int nj = 0; nj < 4; ++nj)
                    #pragma unroll
                    for (int reg = 0; reg < 4; ++reg) {
                        int row = brow + 64 * wr + 16 * mi + 4 * g + reg;
                        int col = bcol + 64 * wc + 16 * nj + l15;
                        int b = row >> 11, t = row & (SEQ - 1);
                        int hh = col >> 6, hd = col & 63;
                        Dst[(size_t)(b * NH + hh) * SEQ * HD
                            + ((size_t)(t >> 3) * 64 + hd) * 8 + (t & 7)] =
                            f2bf(acc[mi][nj][reg]);
                    }
        } else {
            #pragma unroll
            for (int mi = 0; mi < 4; ++mi)
                #pragma unroll
                for (int nj = 0; nj < 4; ++nj)
                    #pragma unroll
                    for (int reg = 0; reg < 4; ++reg) {
                        int row = brow + 64 * wr + 16 * mi + 4 * g + reg;
                        int col = bcol + 64 * wc + 16 * nj + l15;
                        int b = row >> 11, t = row & (SEQ - 1);
                        int hh = col >> 6, hd = col & 63;
                        Dst[(size_t)(b * NH + hh) * SEQ * HD
                            + (((size_t)(t >> 5) * 8 + (hd >> 3)) * 32 + (t & 31)) * 8
                            + (hd & 7)] = f2bf(acc[mi][nj][reg] * osc);
                    }
        }
    } else {
        #pragma unroll
        for (int nj = 0; nj < 4; ++nj) {
            int col = bcol + 64 * wc + 16 * nj + l15;
            float bv = bias[col];
            #pragma unroll
            for (int mi = 0; mi < 4; ++mi)
                #pragma unroll
                for (int reg = 0; reg < 4; ++reg) {
                    int row = brow + 64 * wr + 16 * mi + 4 * g + reg;
                    Fout[(size_t)row * DIM + col] = acc[mi][nj][reg] + bv;
                }
        }
    }
}

// ---------------------------------------------------------------------------
// Flash attention v5: 1 wave/block, QBLK=32, zero barriers, coalesced
// fragment-major loads; K AND V double-buffered in regs; grid = (bh, qt)
// so linear-id%8 = bh%8 -> each XCD's L2 serves exactly 4 heads (2MB K+V);
// qt = 63-y -> longest blocks dispatch first.
// ---------------------------------------------------------------------------
__global__ __launch_bounds__(64, 2)
void attn_mfma5(const ushort* __restrict__ q, const ushort* __restrict__ k,
                const ushort* __restrict__ vt, ushort* __restrict__ ctx)
{
    __shared__ __align__(16) ushort Ob[32 * 64];   // output bounce only (4KB)

    const int l = threadIdx.x;
    const int l31 = l & 31, h = l >> 5;
    const int bh = blockIdx.x;                // 0..31: XCD affinity = bh%8
    const int qt = 63 - (int)blockIdx.y;      // longest-first
    const int qlo = qt * 32;
    const int last = qt >> 1;
    const float LOG2E = 1.44269504f;

    const ushort* Qg = q  + (size_t)bh * SEQ * HD;
    const ushort* Kg = k  + (size_t)bh * SEQ * HD;
    const ushort* Vg = vt + (size_t)bh * SEQ * HD;

    // Q B-frags: coalesced chunk ((qt*8 + 2s+h)*32 + l31)
    bf16x8 qf[4];
    #pragma unroll
    for (int s = 0; s < 4; ++s)
        qf[s] = *(const bf16x8*)&Qg[(((size_t)qt * 8 + 2 * s + h) * 32 + l31) * 8];

    f32x16 o[2] = {};
    float m = -3.0e38f, lsum = 0.f;

    bf16x8 kfA[8], kfB[8], vfA[8], vfB[8];
    #pragma unroll
    for (int s = 0; s < 4; ++s)
        #pragma unroll
        for (int f = 0; f < 2; ++f)
            kfA[2 * s + f] = *(const bf16x8*)
                &Kg[(((size_t)f * 8 + 2 * s + h) * 32 + l31) * 8];
    #pragma unroll
    for (int s4 = 0; s4 < 4; ++s4)
        #pragma unroll
        for (int dt = 0; dt < 2; ++dt)
            vfA[2 * s4 + dt] = *(const bf16x8*)
                &Vg[(((size_t)(2 * s4 + h)) * 64 + 32 * dt + l31) * 8];

    auto body = [&](bf16x8 (&kc)[8], bf16x8 (&kn)[8],
                    bf16x8 (&vc)[8], bf16x8 (&vn)[8], int kt) {
        const int kvb = 64 * kt;

        // S^T = K · Q^T
        f32x16 st[2] = {};
        #pragma unroll
        for (int s = 0; s < 4; ++s)
            #pragma unroll
            for (int f = 0; f < 2; ++f)
                st[f] = __builtin_amdgcn_mfma_f32_32x32x16_bf16(
                    kc[2 * s + f], qf[s], st[f], 0, 0, 0);

        // prefetch next K and V tiles (latency hides under softmax + PV)
        if (kt < last) {
            #pragma unroll
            for (int s = 0; s < 4; ++s)
                #pragma unroll
                for (int f = 0; f < 2; ++f)
                    kn[2 * s + f] = *(const bf16x8*)
                        &Kg[(((size_t)(2 * kt + 2 + f) * 8 + 2 * s + h) * 32 + l31) * 8];
            #pragma unroll
            for (int s4 = 0; s4 < 4; ++s4)
                #pragma unroll
                for (int dt = 0; dt < 2; ++dt)
                    vn[2 * s4 + dt] = *(const bf16x8*)
                        &Vg[(((size_t)(8 * kt + 8 + 2 * s4 + h)) * 64 + 32 * dt + l31) * 8];
        }

        // causal mask (only straddling tile)
        const int qg = qlo + l31;
        if (kvb + 63 > qlo) {
            #pragma unroll
            for (int f = 0; f < 2; ++f)
                #pragma unroll
                for (int r = 0; r < 16; ++r) {
                    int kvg = kvb + 32 * f + (r & 3) + 8 * (r >> 2) + 4 * h;
                    if (kvg > qg) st[f][r] = -INFINITY;
                }
        }

        // row max, tree
        float mx[8];
        #pragma unroll
        for (int i2 = 0; i2 < 8; ++i2) {
            const int f = i2 >> 2, rb = 4 * (i2 & 3);
            mx[i2] = fmaxf(fmaxf(st[f][rb], st[f][rb + 1]),
                           fmaxf(st[f][rb + 2], st[f][rb + 3]));
        }
        float tmax = fmaxf(fmaxf(fmaxf(mx[0], mx[1]), fmaxf(mx[2], mx[3])),
                           fmaxf(fmaxf(mx[4], mx[5]), fmaxf(mx[6], mx[7])));
        tmax = fmaxf(tmax, __shfl_xor(tmax, 32));
        float ty = fmaxf(tmax * LOG2E, -3.0e38f);

        if (!__all(ty - m <= 8.0f)) {            // T13 defer-max
            float mn = fmaxf(m, ty);
            float sc = exp2f(m - mn);
            lsum *= sc;
            #pragma unroll
            for (int dt = 0; dt < 2; ++dt)
                #pragma unroll
                for (int r = 0; r < 16; ++r) o[dt][r] *= sc;
            m = mn;
        }

        // exp + partial sums
        float ls0 = 0.f, ls1 = 0.f, ls2 = 0.f, ls3 = 0.f;
        #pragma unroll
        for (int f = 0; f < 2; ++f)
            #pragma unroll
            for (int r = 0; r < 16; ++r) {
                float pv = exp2f(fmaf(st[f][r], LOG2E, -m));
                st[f][r] = pv;
                if ((r & 3) == 0) ls0 += pv;
                else if ((r & 3) == 1) ls1 += pv;
                else if ((r & 3) == 2) ls2 += pv;
                else ls3 += pv;
            }
        lsum += (ls0 + ls1) + (ls2 + ls3);

        // P -> PA frags (cvt_pk + half-wave exchange), PV MFMAs
        #pragma unroll
        for (int s4 = 0; s4 < 4; ++s4) {
            const int f = s4 >> 1, rb2 = 8 * (s4 & 1);
            unsigned Aa = cvtpk_bf16(st[f][rb2 + 0], st[f][rb2 + 1]);
            unsigned Bb = cvtpk_bf16(st[f][rb2 + 2], st[f][rb2 + 3]);
            unsigned Cc = cvtpk_bf16(st[f][rb2 + 4], st[f][rb2 + 5]);
            unsigned Dd = cvtpk_bf16(st[f][rb2 + 6], st[f][rb2 + 7]);
            unsigned Ax = (unsigned)__shfl_xor((int)Aa, 32);
            unsigned Bx = (unsigned)__shfl_xor((int)Bb, 32);
            unsigned Cx = (unsigned)__shfl_xor((int)Cc, 32);
            unsigned Dx = (unsigned)__shfl_xor((int)Dd, 32);
            union { unsigned wv[4]; bf16x8 v; } pu;
            pu.wv[0] = h ? Cx : Aa;
            pu.wv[1] = h ? Dx : Bb;
            pu.wv[2] = h ? Cc : Ax;
            pu.wv[3] = h ? Dd : Bx;
            #pragma unroll
            for (int dt = 0; dt < 2; ++dt)
                o[dt] = __builtin_amdgcn_mfma_f32_32x32x16_bf16(
                    vc[2 * s4 + dt], pu.v, o[dt], 0, 0, 0);
        }
    };

    int kt = 0;
    while (true) {
        body(kfA, kfB, vfA, vfB, kt);
        if (++kt > last) break;
        body(kfB, kfA, vfB, vfA, kt);
        if (++kt > last) break;
    }

    // normalize + write (coalesce via 4KB LDS bounce)
    float lt = lsum + __shfl_xor(lsum, 32);
    float inv = 1.0f / lt;

    #pragma unroll
    for (int dt = 0; dt < 2; ++dt)
        #pragma unroll
        for (int r = 0; r < 16; r += 2) {
            int d = 32 * dt + (r & 3) + 8 * (r >> 2) + 4 * h;
            unsigned wrd = cvtpk_bf16(o[dt][r] * inv, o[dt][r + 1] * inv);
            *(unsigned*)&Ob[l31 * 64 + (((d >> 3) ^ (l31 & 7)) * 8) + (d & 7)] = wrd;
        }
    asm volatile("s_waitcnt lgkmcnt(0)" ::: "memory");
    __builtin_amdgcn_sched_barrier(0);

    ushort* Cg = ctx + (size_t)bh * SEQ * HD + (size_t)qlo * HD;
    #pragma unroll
    for (int i = 0; i < 4; ++i) {
        int qq = l >> 1, c = (l & 1) * 4 + i;
        int4 vvv = *(const int4*)&Ob[qq * 64 + ((c ^ (qq & 7)) * 8)];
        *(int4*)&Cg[qq * 64 + c * 8] = vvv;
    }
}

// ---------------------------------------------------------------------------
extern "C" void kernel_launch(void* const* d_in, const int* in_sizes, int n_in,
                              void* d_out, int out_size, void* d_ws, size_t ws_size,
                              hipStream_t stream)
{
    (void)in_sizes; (void)n_in; (void)out_size; (void)ws_size;
    const float* x  = (const float*)d_in[0];
    const float* Wq = (const float*)d_in[1];
    const float* Wk = (const float*)d_in[2];
    const float* Wv = (const float*)d_in[3];
    const float* Wo = (const float*)d_in[4];
    const float* bo = (const float*)d_in[5];
    float* out = (float*)d_out;

    ushort* wsu  = (ushort*)d_ws;
    ushort* xb   = wsu;                      // 4M
    ushort* wqb  = wsu + 4194304;            // 1M each
    ushort* wkb  = wsu + 5242880;
    ushort* wvb  = wsu + 6291456;
    ushort* wob  = wsu + 7340032;
    ushort* qbuf = wsu + 8388608;            // 4M, Q fragment-major, *0.125
    ushort* kbuf = wsu + 12582912;           // 4M, K fragment-major
    ushort* vtb  = wsu + 16777216;           // 4M, V^T fragment-major
    ushort* ctxb = wsu + 20971520;           // 4M, flat == [B*T, D]

    cast_all<<<dim3(512, 5), 256, 0, stream>>>(x, Wq, Wk, Wv, Wo,
                                               xb, wqb, wkb, wvb, wob);

    dim3 gqkv(MTOT / 128, DIM / 128, 3);
    gemm_bf16<0><<<gqkv, 256, 0, stream>>>(xb, wqb, wkb, wvb,
                                           qbuf, kbuf, vtb, nullptr, nullptr);

    dim3 ga(BATCH * NH, SEQ / 32);
    attn_mfma5<<<ga, 64, 0, stream>>>(qbuf, kbuf, vtb, ctxb);

    dim3 go(MTOT / 128, DIM / 128, 1);
    gemm_bf16<1><<<go, 256, 0, stream>>>(ctxb, wob, nullptr, nullptr,
                                         nullptr, nullptr, nullptr, bo, out);
}